// Round 1
// baseline (105.546 us; speedup 1.0000x reference)
//
#include <hip/hip_runtime.h>
#include <stdint.h>

#define AS1 __attribute__((address_space(1)))
#define AS3 __attribute__((address_space(3)))

typedef short short8 __attribute__((ext_vector_type(8)));
typedef float floatx4 __attribute__((ext_vector_type(4)));
typedef unsigned int u32;
typedef unsigned short u16;

// Problem constants
#define BB 2048
#define DD 256
#define NN 4096
#define NSPLIT 8
#define COLS_PER_SPLIT (NN / NSPLIT)   // 512
#define ITERS (COLS_PER_SPLIT / 16)    // 32

// ws layout (bytes). Total ~2.72 MB.
#define CB_OFF 0u                       // bf16 contrast features [4096][256], 2 MB
#define PK_OFF (2u * 1024u * 1024u)     // packed label bitsets uint4[2048], 32 KB
#define ST_OFF (PK_OFF + 32u * 1024u)   // row stats: 5 arrays of [8][4096] f32, 640 KB
#define STAT_N (NSPLIT * NN)            // 32768 floats per stat array

__device__ __forceinline__ u16 f2bf(float x) {
  u32 u = __float_as_uint(x);
  u32 r = (u + 0x7fffu + ((u >> 16) & 1u)) >> 16;  // RNE
  return (u16)r;
}

// ---------------- Kernel 1: convert features -> bf16 (view-major, scaled by 1/sqrt(T)) + pack labels
__global__ __launch_bounds__(256) void prep_kernel(const float* __restrict__ feat,
                                                   const int* __restrict__ labels,
                                                   char* __restrict__ ws) {
  const int bx = blockIdx.x, tid = threadIdx.x;
  if (bx < 1024) {
    // 1024*256 threads * 4 elems = 1,048,576 = 4096*256
    u16* cb = (u16*)(ws + CB_OFF);
    int t = bx * 256 + tid;
    int n = t >> 6;            // contrast row 0..4095
    int d = (t & 63) << 2;     // d offset, 4 at a time
    // contrast[n] = features[n % B][n / B]  (view-major stacking)
    size_t src = ((size_t)((n & 2047) * 2 + (n >> 11))) * 256 + d;
    const float4 f = *(const float4*)(feat + src);
    const float s0 = 3.7796447300922722f;  // 1/sqrt(0.07): dot of scaled == dot/T
    u16 o0 = f2bf(f.x * s0), o1 = f2bf(f.y * s0), o2 = f2bf(f.z * s0), o3 = f2bf(f.w * s0);
    ushort4 o; o.x = o0; o.y = o1; o.z = o2; o.w = o3;
    *(ushort4*)(cb + (size_t)n * 256 + d) = o;
  } else if (bx < 1032) {
    int b = (bx - 1024) * 256 + tid;   // 0..2047
    const int* lp = labels + (size_t)b * 80;
    u32 lo = 0, mid = 0, hi = 0;
    #pragma unroll
    for (int k = 0; k < 32; ++k) lo  |= (u32)(lp[k]      != 0) << k;
    #pragma unroll
    for (int k = 0; k < 32; ++k) mid |= (u32)(lp[32 + k] != 0) << k;
    #pragma unroll
    for (int k = 0; k < 16; ++k) hi  |= (u32)(lp[64 + k] != 0) << k;
    u32 cnt = (u32)(__popc(lo) + __popc(mid) + __popc(hi));
    uint4* pk = (uint4*)(ws + PK_OFF);
    uint4 v; v.x = lo; v.y = mid; v.z = hi; v.w = cnt;
    pk[b] = v;
  }
}

// ---------------- Kernel 2: main flash-style pass.
// Grid 512 = 64 row-blocks x 8 col-splits. Block: 64 rows, 4 waves x 16 rows each,
// iterating 16-col tiles over its 512-col span. MFMA 16x16x32 bf16, A-frags in regs,
// B staged via global_load_lds with XOR swizzle (chunk ^= row&7) for bank-conflict-free ds_read_b128.
__global__ __launch_bounds__(256) void main_kernel(char* __restrict__ ws) {
  const u16* __restrict__ cb = (const u16*)(ws + CB_OFF);
  const uint4* __restrict__ pk = (const uint4*)(ws + PK_OFF);
  float* __restrict__ stat = (float*)(ws + ST_OFF);

  __shared__ char lds[40 * 1024];  // A: [0,32K)  B: [32K,40K)

  const int tid = threadIdx.x;
  const int w = tid >> 6, lane = tid & 63;
  const int n = lane & 15, q = lane >> 4;
  const int rb = blockIdx.x & 63;
  const int cs = blockIdx.x >> 6;
  const int rowb = rb * 64;
  const int row_wave = rowb + w * 16;
  const int cbase0 = cs * COLS_PER_SPLIT;

  // ---- stage A tile (64 rows x 256 k, 32 KB) + first B tile (16 rows x 256 k, 8 KB)
  {
    const char* gb = (const char*)cb;
    #pragma unroll
    for (int p = 0; p < 8; ++p) {
      int c = p * 256 + tid;
      int ar = c >> 5, kc = c & 31;
      const char* g = gb + (size_t)(rowb + ar) * 512 + (size_t)((kc ^ (ar & 7)) << 4);
      __builtin_amdgcn_global_load_lds((AS1 const void*)g,
                                       (AS3 void*)(lds + p * 4096 + w * 1024), 16, 0, 0);
    }
    #pragma unroll
    for (int p = 0; p < 2; ++p) {
      int c = p * 256 + tid;
      int br = c >> 5, kc = c & 31;
      const char* g = gb + (size_t)(cbase0 + br) * 512 + (size_t)((kc ^ (br & 7)) << 4);
      __builtin_amdgcn_global_load_lds((AS1 const void*)g,
                                       (AS3 void*)(lds + 32768 + p * 4096 + w * 1024), 16, 0, 0);
    }
  }

  // row-side label bitsets (fixed for whole kernel)
  uint4 rpk[4];
  #pragma unroll
  for (int r = 0; r < 4; ++r) rpk[r] = pk[(row_wave + (q << 2) + r) & 2047];

  __syncthreads();

  // ---- A fragments to registers: lane holds A[m=lane&15][k = q*8 + j] per 32-k step
  short8 afr[8];
  #pragma unroll
  for (int kk = 0; kk < 8; ++kk) {
    int chunk = ((kk << 2) | q) ^ (n & 7);
    afr[kk] = *(const short8*)(lds + (size_t)((w * 16 + n) * 512) + (chunk << 4));
  }

  float M[4], S[4], Aw[4], Wsum[4], P[4];
  #pragma unroll
  for (int r = 0; r < 4; ++r) { M[r] = -__builtin_inff(); S[r] = 0.f; Aw[r] = 0.f; Wsum[r] = 0.f; P[r] = 0.f; }

  for (int it = 0; it < ITERS; ++it) {
    const int col_g = cbase0 + it * 16 + n;   // this lane's column (fixed per iter)
    const uint4 cpk = pk[col_g & 2047];

    floatx4 acc = {0.f, 0.f, 0.f, 0.f};
    #pragma unroll
    for (int kk = 0; kk < 8; ++kk) {
      int chunk = ((kk << 2) | q) ^ (n & 7);
      short8 bfr = *(const short8*)(lds + 32768 + (size_t)(n * 512) + (chunk << 4));
      acc = __builtin_amdgcn_mfma_f32_16x16x32_bf16(afr[kk], bfr, acc, 0, 0, 0);
    }

    #pragma unroll
    for (int r = 0; r < 4; ++r) {
      float s = acc[r];                               // sims (already includes /T)
      int row_g = row_wave + (q << 2) + r;
      bool diag = (row_g == col_g);
      // online softmax (max over ALL j incl diagonal; sum excludes diagonal)
      float mn = fmaxf(M[r], s);
      float d = diag ? 0.0f : __expf(s - mn);
      S[r] = S[r] * __expf(M[r] - mn) + d;
      M[r] = mn;
      // jaccard from bitsets; mask exact via 10*inter >= 3*union (and inter>0)
      u32 inter = (u32)(__popc(rpk[r].x & cpk.x) + __popc(rpk[r].y & cpk.y) + __popc(rpk[r].z & cpk.z));
      u32 uni = rpk[r].w + cpk.w - inter;
      bool msk = (10u * inter >= 3u * uni) && (inter > 0u) && !diag;
      float jac = (float)inter * __builtin_amdgcn_rcpf((float)uni);
      float wv = msk ? jac * 3.3333332539e0f : 0.0f;  // jaccard / 0.3f
      Aw[r] = fmaf(wv, s, Aw[r]);
      Wsum[r] += wv;
      P[r] += msk ? 1.0f : 0.0f;
    }

    __syncthreads();                 // all waves done reading B tile
    if (it + 1 < ITERS) {
      #pragma unroll
      for (int p = 0; p < 2; ++p) {
        int c = p * 256 + tid;
        int br = c >> 5, kc = c & 31;
        const char* g = (const char*)cb + (size_t)(cbase0 + (it + 1) * 16 + br) * 512 +
                        (size_t)((kc ^ (br & 7)) << 4);
        __builtin_amdgcn_global_load_lds((AS1 const void*)g,
                                         (AS3 void*)(lds + 32768 + p * 4096 + w * 1024), 16, 0, 0);
      }
    }
    __syncthreads();                 // staged (compiler drains vmcnt before barrier)
  }

  // ---- reduce across the 16 lanes sharing each row (same q, n = 0..15)
  #pragma unroll
  for (int r = 0; r < 4; ++r) {
    #pragma unroll
    for (int msk = 1; msk < 16; msk <<= 1) {
      float M2 = __shfl_xor(M[r], msk);
      float S2 = __shfl_xor(S[r], msk);
      float A2 = __shfl_xor(Aw[r], msk);
      float W2 = __shfl_xor(Wsum[r], msk);
      float P2 = __shfl_xor(P[r], msk);
      float mn = fmaxf(M[r], M2);
      S[r] = S[r] * __expf(M[r] - mn) + S2 * __expf(M2 - mn);
      M[r] = mn;
      Aw[r] += A2; Wsum[r] += W2; P[r] += P2;
    }
  }
  if (n == 0) {
    #pragma unroll
    for (int r = 0; r < 4; ++r) {
      int row_g = row_wave + (q << 2) + r;
      int idx = cs * NN + row_g;
      stat[idx] = M[r];
      stat[STAT_N + idx] = S[r];
      stat[2 * STAT_N + idx] = Aw[r];
      stat[3 * STAT_N + idx] = Wsum[r];
      stat[4 * STAT_N + idx] = P[r];
    }
  }
}

// ---------------- Kernel 3: merge 8 col-splits per row, compute loss
__global__ __launch_bounds__(1024) void merge_final(const char* __restrict__ ws,
                                                    float* __restrict__ out) {
  const float* stat = (const float*)(ws + ST_OFF);
  const int tid = threadIdx.x;
  float local = 0.f;
  #pragma unroll
  for (int rr = 0; rr < 4; ++rr) {
    int row = tid + rr * 1024;
    float m = stat[row];
    float S = stat[STAT_N + row];
    float A = stat[2 * STAT_N + row];
    float W = stat[3 * STAT_N + row];
    float P = stat[4 * STAT_N + row];
    for (int cs = 1; cs < NSPLIT; ++cs) {
      int idx = cs * NN + row;
      float m2 = stat[idx];
      float S2 = stat[STAT_N + idx];
      float mn = fmaxf(m, m2);
      S = S * __expf(m - mn) + S2 * __expf(m2 - mn);
      m = mn;
      A += stat[2 * STAT_N + idx];
      W += stat[3 * STAT_N + idx];
      P += stat[4 * STAT_N + idx];
    }
    // sum_j wm*(s - M - log(S+eps)) / (P + eps)
    float rowval = (A - (m + logf(S + 1e-8f)) * W) / (P + 1e-8f);
    local += rowval;
  }
  __shared__ float red[16];
  #pragma unroll
  for (int msk = 32; msk >= 1; msk >>= 1) local += __shfl_xor(local, msk);
  if ((tid & 63) == 0) red[tid >> 6] = local;
  __syncthreads();
  if (tid < 64) {
    float v = (tid < 16) ? red[tid] : 0.f;
    #pragma unroll
    for (int msk = 8; msk >= 1; msk >>= 1) v += __shfl_xor(v, msk);
    if (tid == 0) out[0] = -0.07f * v * (1.0f / 4096.0f);
  }
}

extern "C" void kernel_launch(void* const* d_in, const int* in_sizes, int n_in,
                              void* d_out, int out_size, void* d_ws, size_t ws_size,
                              hipStream_t stream) {
  const float* feat = (const float*)d_in[0];   // [2048,2,256] f32
  const int* labels = (const int*)d_in[1];     // [2048,80] i32
  char* ws = (char*)d_ws;                      // needs ~2.8 MB
  float* out = (float*)d_out;                  // scalar f32

  prep_kernel<<<1032, 256, 0, stream>>>(feat, labels, ws);
  main_kernel<<<512, 256, 0, stream>>>(ws);
  merge_final<<<1, 1024, 0, stream>>>(ws, out);
}